// Round 5
// baseline (238.531 us; speedup 1.0000x reference)
//
#include <hip/hip_runtime.h>

typedef unsigned short USH;
typedef unsigned int   UIN;

static constexpr int Bn = 1024;    // batch
static constexpr int Hn = 200;     // history length
static constexpr int Dn = 128;     // embed/hidden
static constexpr int Dh = 64;      // half embed
static constexpr int NITEM = 50000;
static constexpr int NREG  = 1000;
static constexpr int AB_A_BLOCKS = (NITEM + 63) / 64;  // 782
static constexpr int AB_B_BLOCKS = (NREG  + 63) / 64;  // 16

__device__ __forceinline__ float bf2f(USH u) {
  return __uint_as_float(((UIN)u) << 16);
}
__device__ __forceinline__ float2 pb2f2(UIN p) {  // packed bf16 pair -> 2 floats
  float2 r;
  r.x = __uint_as_float(p << 16);
  r.y = __uint_as_float(p & 0xffff0000u);
  return r;
}
__device__ __forceinline__ USH f2b(float f) {  // fp32 -> bf16 rne
  UIN x = __float_as_uint(f);
  return (USH)((x + 0x7fffu + ((x >> 16) & 1u)) >> 16);
}

// ---------------------------------------------------------------------------
// g[c] = sum_i row[tr[i]] * row[hr[i,c]],  row = embed_dist[uid]  (fp32)
// ---------------------------------------------------------------------------
__global__ __launch_bounds__(256) void g_kernel(
    const int* __restrict__ hregion, const int* __restrict__ tregion,
    const float* __restrict__ embed_dist, const int* __restrict__ uid,
    float* __restrict__ g) {
  int c = threadIdx.x;
  const float* row = embed_dist + (size_t)uid[0] * NREG;  // 4KB, L1-resident
  float acc = 0.f;
  int ibase = blockIdx.x * 16;
  for (int ii = 0; ii < 16; ii++) {
    int i = ibase + ii;
    float td = row[tregion[i]];               // wave-uniform broadcast
    if (c < Hn) acc += td * row[hregion[(size_t)i * Hn + c]];
  }
  if (c < Hn) atomicAdd(&g[c], acc);
}

// ---------------------------------------------------------------------------
// A[item][j] = dot(Et[item][0:64], Wk[j][0:64])   -> bf16 table
// B[reg][j]  = dot(Er[reg][0:64],  Wk[j][64:128]) -> bf16 table
// v4: NO LDS. Thread j loads its Wk half-row (contiguous 256B) from global
// once, then asm-pins wkf[64] into VGPRs so the compiler CANNOT rematerialize
// per-item (rounds 3-4: VGPR=52, wkf folded to 3.3GB of LDS re-reads).
// Inner loop: wave-uniform E-row loads + 64 reg-resident FMAs per item.
// ---------------------------------------------------------------------------
__global__ __launch_bounds__(256, 1) void ab_kernel(
    const float* __restrict__ Et, const float* __restrict__ Er,
    const float* __restrict__ Wk, USH* __restrict__ A, USH* __restrict__ Bt) {
  int blk = blockIdx.x, tid = threadIdx.x;
  const float* E; USH* Out; int nmax, base, koff;
  if (blk < AB_A_BLOCKS) { E = Et; Out = A;  nmax = NITEM; base = blk * 64; koff = 0; }
  else { E = Er; Out = Bt; nmax = NREG; base = (blk - AB_A_BLOCKS) * 64; koff = 64; }

  int j = tid & 127, g = tid >> 7;  // g wave-uniform
  float wkf[64];                    // register-resident Wk column j
  {
    const float4* wp = reinterpret_cast<const float4*>(Wk + (size_t)j * Dn + koff);
#pragma unroll
    for (int k4 = 0; k4 < 16; k4++) {
      float4 w = wp[k4];
      wkf[k4 * 4 + 0] = w.x; wkf[k4 * 4 + 1] = w.y;
      wkf[k4 * 4 + 2] = w.z; wkf[k4 * 4 + 3] = w.w;
    }
  }
#pragma unroll
  for (int k = 0; k < 64; k++) asm volatile("" : "+v"(wkf[k]));  // pin to VGPR

#pragma unroll 2
  for (int ii = 0; ii < 32; ii++) {
    int item = base + g * 32 + ii;
    if (item < nmax) {
      const float4* ep = reinterpret_cast<const float4*>(E + (size_t)item * Dh);
      float a0 = 0.f, a1 = 0.f, a2 = 0.f, a3 = 0.f;  // 4 dep chains
#pragma unroll
      for (int k4 = 0; k4 < 16; k4++) {
        float4 e = ep[k4];
        a0 += e.x * wkf[k4 * 4 + 0];
        a1 += e.y * wkf[k4 * 4 + 1];
        a2 += e.z * wkf[k4 * 4 + 2];
        a3 += e.w * wkf[k4 * 4 + 3];
      }
      Out[(size_t)item * Dn + j] = f2b((a0 + a1) + (a2 + a3));
    }
  }
}

// ---------------------------------------------------------------------------
// One block per batch row i. v5: kv[t][j]=A+B staged in LDS as bf16 (51.2KB,
// coalesced 8B/lane loads). Score gather becomes pure LDS: halfword index
// t*128+j == m == a*200+c, so the inner loop is ds_read_u16+fma with zero
// address math and conflict-free banking. qv/uv computed with all 256
// threads (split-K partials).
// ---------------------------------------------------------------------------
__global__ __launch_bounds__(256, 2) void main_kernel(
    const int* __restrict__ history, const int* __restrict__ target,
    const int* __restrict__ hregion, const int* __restrict__ tregion,
    const float* __restrict__ hv, const float* __restrict__ dist_mat,
    const float* __restrict__ Et, const float* __restrict__ Er,
    const float* __restrict__ Wq, const float* __restrict__ Wv,
    const float* __restrict__ g, const USH* __restrict__ A,
    const USH* __restrict__ Bt, float* __restrict__ out) {
  __shared__ USH kvs[Hn * Dn];      // 51.2KB: kv[t][j] bf16
  __shared__ float tgtE[128], qv[128], uv[128];
  __shared__ float qp[256], up[256];
  __shared__ int li[Hn], lr[Hn];
  __shared__ float red[8];
  int i = blockIdx.x, tid = threadIdx.x, lane = tid & 63, wave = tid >> 6;
  int tgt_i = target[i], tr_i = tregion[i];
  const int* hrow = history + (size_t)i * Hn;
  const int* rrow = hregion + (size_t)i * Hn;

  if (tid < Hn) { li[tid] = hrow[tid]; lr[tid] = rrow[tid]; }
  if (tid < 64)       tgtE[tid] = Et[(size_t)tgt_i * Dh + tid];
  else if (tid < 128) tgtE[tid] = Er[(size_t)tr_i * Dh + (tid - 64)];
  __syncthreads();

  // ---- stage kv[t][j] = A[li[t]][j] + B[lr[t]][j] (bf16) ----
  // 8 rows/pass, 32 lanes/row, 4 bf16 (8B) per lane, 25 passes.
  {
    int rlane = tid & 31, rgrp = tid >> 5;
#pragma unroll 5
    for (int p = 0; p < 25; p++) {
      int t = p * 8 + rgrp;
      int ia = li[t], ib = lr[t];
      uint2 av = *reinterpret_cast<const uint2*>(A  + (size_t)ia * Dn + rlane * 4);
      uint2 bv = *reinterpret_cast<const uint2*>(Bt + (size_t)ib * Dn + rlane * 4);
      float2 a0 = pb2f2(av.x), a1 = pb2f2(av.y);
      float2 b0 = pb2f2(bv.x), b1 = pb2f2(bv.y);
      uint2 pk;
      pk.x = (UIN)f2b(a0.x + b0.x) | ((UIN)f2b(a0.y + b0.y) << 16);
      pk.y = (UIN)f2b(a1.x + b1.x) | ((UIN)f2b(a1.y + b1.y) << 16);
      *reinterpret_cast<uint2*>(&kvs[t * Dn + rlane * 4]) = pk;
    }
  }

  // ---- qv/uv partials with all 256 threads (split K/J halves) ----
  {
    int jq = tid & 127, hq = tid >> 7;  // hq: which half of the reduction
    const float4* wqp = reinterpret_cast<const float4*>(Wq + (size_t)jq * Dn + hq * 64);
    float qa = 0.f;
#pragma unroll
    for (int k4 = 0; k4 < 16; k4++) {
      float4 w = wqp[k4];
      const float* tv = &tgtE[hq * 64 + k4 * 4];
      qa += w.x * tv[0] + w.y * tv[1] + w.z * tv[2] + w.w * tv[3];
    }
    qp[tid] = qa;
    float ua = 0.f;
#pragma unroll 8
    for (int jj = 0; jj < 64; jj++)
      ua += Wv[(size_t)(hq * 64 + jj) * Dn + jq] * tgtE[hq * 64 + jj];
    up[tid] = ua;
  }
  __syncthreads();
  if (tid < 128) {
    qv[tid] = (qp[tid] + qp[tid + 128]) * 0.088388347648318447f;  // 1/sqrt(128)
    uv[tid] = up[tid] + up[tid + 128];
  }
  __syncthreads();

  float ea = 0.f, sc1 = 0.f, sc2 = 0.f;
  if (tid < Hn) {
    // scores[c]: kvs halfword index == m == a*200+c  (zero address math)
    int c = tid;
    float acc = 0.f;
    const USH* kp = &kvs[c];
#pragma unroll 16
    for (int a = 0; a < 128; a++) acc += qv[a] * bf2f(kp[a * 200]);
    // s1/s2: per-thread dot over own history row
    int t = tid;
    const float4* ep = reinterpret_cast<const float4*>(Et + (size_t)li[t] * Dh);
    const float4* rp = reinterpret_cast<const float4*>(Er + (size_t)lr[t] * Dh);
    float p1 = 0.f, p2 = 0.f;
#pragma unroll
    for (int k4 = 0; k4 < 16; k4++) {
      float4 e = ep[k4], r = rp[k4];
      const float* u0 = &uv[k4 * 4];        const float* t0 = &tgtE[k4 * 4];
      const float* u1 = &uv[64 + k4 * 4];   const float* t1 = &tgtE[64 + k4 * 4];
      p1 += e.x * u0[0] + e.y * u0[1] + e.z * u0[2] + e.w * u0[3]
          + r.x * u1[0] + r.y * u1[1] + r.z * u1[2] + r.w * u1[3];
      p2 += e.x * t0[0] + e.y * t0[1] + e.z * t0[2] + e.w * t0[3]
          + r.x * t1[0] + r.y * t1[1] + r.z * t1[2] + r.w * t1[3];
    }
    sc1 = p1; sc2 = p2;
    ea = (li[tid] != tgt_i) ? __expf(acc) : 0.f;  // masked exp(score)
  }

  // exp-sum reduction
  float wsum = ea;
  for (int off = 32; off > 0; off >>= 1) wsum += __shfl_down(wsum, off, 64);
  if (lane == 0) red[wave] = wsum;
  __syncthreads();
  float esum = red[0] + red[1] + red[2] + red[3];
  float inv = esum > 0.f ? 1.f / sqrtf(esum) : 0.f;  // exp_sum ** 0.5 (BETA)

  float part = 0.f;
  if (tid < Hn) {
    float attn = ea * inv;
    float gc = g[tid]; gc = gc > 0.f ? gc : 0.f;  // relu
    float dm = dist_mat[(size_t)i * Hn + tid];
    float geo = __expf(-dm / (gc + 1.f));
    part = (attn + geo) * sc1 + hv[tid] * sc2;
  }
  __syncthreads();  // protect red[] reuse
  for (int off = 32; off > 0; off >>= 1) part += __shfl_down(part, off, 64);
  if (lane == 0) red[wave] = part;
  __syncthreads();
  if (tid == 0) {
    float pred = red[0] + red[1] + red[2] + red[3];
    out[i] = 1.f / (1.f + __expf(-pred));
  }
}

extern "C" void kernel_launch(void* const* d_in, const int* in_sizes, int n_in,
                              void* d_out, int out_size, void* d_ws, size_t ws_size,
                              hipStream_t stream) {
  const int*   history = (const int*)d_in[0];
  const int*   target  = (const int*)d_in[1];
  const int*   hregion = (const int*)d_in[2];
  const int*   tregion = (const int*)d_in[3];
  const float* hv      = (const float*)d_in[4];
  const float* dist    = (const float*)d_in[5];
  const int*   uid     = (const int*)d_in[6];
  const float* Et      = (const float*)d_in[7];
  const float* Er      = (const float*)d_in[8];
  const float* Edist   = (const float*)d_in[9];
  const float* Wq      = (const float*)d_in[10];
  const float* Wk      = (const float*)d_in[11];
  const float* Wv      = (const float*)d_in[12];

  float* g = (float*)d_ws;                          // 200 f32 (1KB slot)
  USH* A   = (USH*)((char*)d_ws + 1024);            // 50000*128 bf16 = 12.8MB
  USH* Bt  = A + (size_t)NITEM * Dn;                // 1000*128 bf16 = 256KB
  float* out = (float*)d_out;

  hipMemsetAsync(g, 0, Hn * sizeof(float), stream);
  g_kernel<<<Bn / 16, 256, 0, stream>>>(hregion, tregion, Edist, uid, g);
  ab_kernel<<<AB_A_BLOCKS + AB_B_BLOCKS, 256, 0, stream>>>(Et, Er, Wk, A, Bt);
  main_kernel<<<Bn, 256, 0, stream>>>(history, target, hregion, tregion, hv, dist,
                                      Et, Er, Wq, Wv, g, A, Bt, out);
}

// Round 6
// 180.024 us; speedup vs baseline: 1.3250x; 1.3250x over previous
//
#include <hip/hip_runtime.h>

typedef unsigned short USH;
typedef unsigned int   UIN;

static constexpr int Bn = 1024;    // batch
static constexpr int Hn = 200;     // history length
static constexpr int Dn = 128;     // embed/hidden
static constexpr int Dh = 64;      // half embed
static constexpr int NITEM = 50000;
static constexpr int NREG  = 1000;
static constexpr int MT = 64;      // items per ab block
static constexpr int AB_A_BLOCKS = (NITEM + MT - 1) / MT;  // 782
static constexpr int AB_B_BLOCKS = (NREG  + MT - 1) / MT;  // 16
static constexpr int WTS = 132;    // wt stride (floats): b128-aligned, low conflict
static constexpr int ETS = 69;     // et stride (floats): 2-way max on reads

__device__ __forceinline__ float bf2f(USH u) {
  return __uint_as_float(((UIN)u) << 16);
}
__device__ __forceinline__ float2 pb2f2(UIN p) {  // packed bf16 pair -> 2 floats
  float2 r;
  r.x = __uint_as_float(p << 16);
  r.y = __uint_as_float(p & 0xffff0000u);
  return r;
}
__device__ __forceinline__ USH f2b(float f) {  // fp32 -> bf16 rne
  UIN x = __float_as_uint(f);
  return (USH)((x + 0x7fffu + ((x >> 16) & 1u)) >> 16);
}

// ---------------------------------------------------------------------------
// g[c] = sum_i row[tr[i]] * row[hr[i,c]],  row = embed_dist[uid]  (fp32)
// ---------------------------------------------------------------------------
__global__ __launch_bounds__(256) void g_kernel(
    const int* __restrict__ hregion, const int* __restrict__ tregion,
    const float* __restrict__ embed_dist, const int* __restrict__ uid,
    float* __restrict__ g) {
  int c = threadIdx.x;
  const float* row = embed_dist + (size_t)uid[0] * NREG;  // 4KB, L1-resident
  float acc = 0.f;
  int ibase = blockIdx.x * 16;
  for (int ii = 0; ii < 16; ii++) {
    int i = ibase + ii;
    float td = row[tregion[i]];               // wave-uniform broadcast
    if (c < Hn) acc += td * row[hregion[(size_t)i * Hn + c]];
  }
  if (c < Hn) atomicAdd(&g[c], acc);
}

// ---------------------------------------------------------------------------
// A[item][j] = dot(Et[item][0:64], Wk[j][0:64])   -> bf16 table
// B[reg][j]  = dot(Er[reg][0:64],  Wk[j][64:128]) -> bf16 table
// v6: register-tiled GEMM. Rounds 3-5 proved the compiler will never keep a
// 64-float loop-INVARIANT array in VGPRs (folds to LDS re-reads or scratch
// spill). So the per-thread register array is now the ACCUMULATOR tile
// (4 items x 8 j), which cannot be rematerialized. Operands stream from LDS:
// wt[k][j] (stride 132) and et[m][k] (stride 69). VALU-bound, ~5.3us floor.
// ---------------------------------------------------------------------------
__global__ __launch_bounds__(256, 2) void ab_kernel(
    const float* __restrict__ Et, const float* __restrict__ Er,
    const float* __restrict__ Wk, USH* __restrict__ A, USH* __restrict__ Bt) {
  __shared__ float wt[64 * WTS];  // 33.8KB: wt[k*WTS + j] = Wk[j][koff+k]
  __shared__ float et[MT * ETS];  // 17.7KB: et[m*ETS + k] = E[base+m][k]
  int blk = blockIdx.x, tid = threadIdx.x;
  const float* E; USH* Out; int nmax, base, koff;
  if (blk < AB_A_BLOCKS) { E = Et; Out = A;  nmax = NITEM; base = blk * MT; koff = 0; }
  else { E = Er; Out = Bt; nmax = NREG; base = (blk - AB_A_BLOCKS) * MT; koff = 64; }

  // stage Wk transposed: lanes 0..15 read one row's 16 quads (coalesced)
#pragma unroll
  for (int p = 0; p < 8; p++) {
    int idx = p * 256 + tid;     // 0..2047
    int row = idx >> 4, c4 = idx & 15;
    float4 w = *reinterpret_cast<const float4*>(Wk + (size_t)row * Dn + koff + c4 * 4);
    wt[(c4 * 4 + 0) * WTS + row] = w.x;
    wt[(c4 * 4 + 1) * WTS + row] = w.y;
    wt[(c4 * 4 + 2) * WTS + row] = w.z;
    wt[(c4 * 4 + 3) * WTS + row] = w.w;
  }
  // stage E rows row-major (no transpose): b32 writes, conflict-light
#pragma unroll
  for (int p = 0; p < 4; p++) {
    int idx = p * 256 + tid;     // 0..1023
    int m = idx >> 4, c4 = idx & 15;
    int gi = base + m;
    float4 e = make_float4(0.f, 0.f, 0.f, 0.f);
    if (gi < nmax) e = *reinterpret_cast<const float4*>(E + (size_t)gi * Dh + c4 * 4);
    et[m * ETS + c4 * 4 + 0] = e.x;
    et[m * ETS + c4 * 4 + 1] = e.y;
    et[m * ETS + c4 * 4 + 2] = e.z;
    et[m * ETS + c4 * 4 + 3] = e.w;
  }
  __syncthreads();

  int jt = tid & 15, it = tid >> 4;     // 8 j's per thread, 4 items per thread
  const float* wb = wt + jt * 8;
  const float* eb = et + (it * 4) * ETS;
  float c[4][8];
#pragma unroll
  for (int ii = 0; ii < 4; ii++)
#pragma unroll
    for (int jj = 0; jj < 8; jj++) c[ii][jj] = 0.f;

#pragma unroll 2
  for (int k = 0; k < 64; k++) {
    float4 w0 = *reinterpret_cast<const float4*>(wb + (size_t)k * WTS);
    float4 w1 = *reinterpret_cast<const float4*>(wb + (size_t)k * WTS + 4);
    float e0 = eb[k], e1 = eb[ETS + k], e2 = eb[2 * ETS + k], e3 = eb[3 * ETS + k];
    c[0][0] += e0 * w0.x; c[0][1] += e0 * w0.y; c[0][2] += e0 * w0.z; c[0][3] += e0 * w0.w;
    c[0][4] += e0 * w1.x; c[0][5] += e0 * w1.y; c[0][6] += e0 * w1.z; c[0][7] += e0 * w1.w;
    c[1][0] += e1 * w0.x; c[1][1] += e1 * w0.y; c[1][2] += e1 * w0.z; c[1][3] += e1 * w0.w;
    c[1][4] += e1 * w1.x; c[1][5] += e1 * w1.y; c[1][6] += e1 * w1.z; c[1][7] += e1 * w1.w;
    c[2][0] += e2 * w0.x; c[2][1] += e2 * w0.y; c[2][2] += e2 * w0.z; c[2][3] += e2 * w0.w;
    c[2][4] += e2 * w1.x; c[2][5] += e2 * w1.y; c[2][6] += e2 * w1.z; c[2][7] += e2 * w1.w;
    c[3][0] += e3 * w0.x; c[3][1] += e3 * w0.y; c[3][2] += e3 * w0.z; c[3][3] += e3 * w0.w;
    c[3][4] += e3 * w1.x; c[3][5] += e3 * w1.y; c[3][6] += e3 * w1.z; c[3][7] += e3 * w1.w;
  }

#pragma unroll
  for (int ii = 0; ii < 4; ii++) {
    int item = base + it * 4 + ii;
    if (item < nmax) {
      uint4 pk;
      pk.x = (UIN)f2b(c[ii][0]) | ((UIN)f2b(c[ii][1]) << 16);
      pk.y = (UIN)f2b(c[ii][2]) | ((UIN)f2b(c[ii][3]) << 16);
      pk.z = (UIN)f2b(c[ii][4]) | ((UIN)f2b(c[ii][5]) << 16);
      pk.w = (UIN)f2b(c[ii][6]) | ((UIN)f2b(c[ii][7]) << 16);
      *reinterpret_cast<uint4*>(Out + (size_t)item * Dn + jt * 8) = pk;
    }
  }
}

// ---------------------------------------------------------------------------
// One block per batch row i. kv[t][j]=A+B staged in LDS as bf16; score gather
// is pure LDS (halfword index t*128+j == m == a*200+c). Unchanged from r5.
// ---------------------------------------------------------------------------
__global__ __launch_bounds__(256, 2) void main_kernel(
    const int* __restrict__ history, const int* __restrict__ target,
    const int* __restrict__ hregion, const int* __restrict__ tregion,
    const float* __restrict__ hv, const float* __restrict__ dist_mat,
    const float* __restrict__ Et, const float* __restrict__ Er,
    const float* __restrict__ Wq, const float* __restrict__ Wv,
    const float* __restrict__ g, const USH* __restrict__ A,
    const USH* __restrict__ Bt, float* __restrict__ out) {
  __shared__ USH kvs[Hn * Dn];      // 51.2KB: kv[t][j] bf16
  __shared__ float tgtE[128], qv[128], uv[128];
  __shared__ float qp[256], up[256];
  __shared__ int li[Hn], lr[Hn];
  __shared__ float red[8];
  int i = blockIdx.x, tid = threadIdx.x, lane = tid & 63, wave = tid >> 6;
  int tgt_i = target[i], tr_i = tregion[i];
  const int* hrow = history + (size_t)i * Hn;
  const int* rrow = hregion + (size_t)i * Hn;

  if (tid < Hn) { li[tid] = hrow[tid]; lr[tid] = rrow[tid]; }
  if (tid < 64)       tgtE[tid] = Et[(size_t)tgt_i * Dh + tid];
  else if (tid < 128) tgtE[tid] = Er[(size_t)tr_i * Dh + (tid - 64)];
  __syncthreads();

  // ---- stage kv[t][j] = A[li[t]][j] + B[lr[t]][j] (bf16) ----
  {
    int rlane = tid & 31, rgrp = tid >> 5;
#pragma unroll 5
    for (int p = 0; p < 25; p++) {
      int t = p * 8 + rgrp;
      int ia = li[t], ib = lr[t];
      uint2 av = *reinterpret_cast<const uint2*>(A  + (size_t)ia * Dn + rlane * 4);
      uint2 bv = *reinterpret_cast<const uint2*>(Bt + (size_t)ib * Dn + rlane * 4);
      float2 a0 = pb2f2(av.x), a1 = pb2f2(av.y);
      float2 b0 = pb2f2(bv.x), b1 = pb2f2(bv.y);
      uint2 pk;
      pk.x = (UIN)f2b(a0.x + b0.x) | ((UIN)f2b(a0.y + b0.y) << 16);
      pk.y = (UIN)f2b(a1.x + b1.x) | ((UIN)f2b(a1.y + b1.y) << 16);
      *reinterpret_cast<uint2*>(&kvs[t * Dn + rlane * 4]) = pk;
    }
  }

  // ---- qv/uv partials with all 256 threads (split K/J halves) ----
  {
    int jq = tid & 127, hq = tid >> 7;
    const float4* wqp = reinterpret_cast<const float4*>(Wq + (size_t)jq * Dn + hq * 64);
    float qa = 0.f;
#pragma unroll
    for (int k4 = 0; k4 < 16; k4++) {
      float4 w = wqp[k4];
      const float* tv = &tgtE[hq * 64 + k4 * 4];
      qa += w.x * tv[0] + w.y * tv[1] + w.z * tv[2] + w.w * tv[3];
    }
    qp[tid] = qa;
    float ua = 0.f;
#pragma unroll 8
    for (int jj = 0; jj < 64; jj++)
      ua += Wv[(size_t)(hq * 64 + jj) * Dn + jq] * tgtE[hq * 64 + jj];
    up[tid] = ua;
  }
  __syncthreads();
  if (tid < 128) {
    qv[tid] = (qp[tid] + qp[tid + 128]) * 0.088388347648318447f;  // 1/sqrt(128)
    uv[tid] = up[tid] + up[tid + 128];
  }
  __syncthreads();

  float ea = 0.f, sc1 = 0.f, sc2 = 0.f;
  if (tid < Hn) {
    int c = tid;
    float acc = 0.f;
    const USH* kp = &kvs[c];
#pragma unroll 16
    for (int a = 0; a < 128; a++) acc += qv[a] * bf2f(kp[a * 200]);
    int t = tid;
    const float4* ep = reinterpret_cast<const float4*>(Et + (size_t)li[t] * Dh);
    const float4* rp = reinterpret_cast<const float4*>(Er + (size_t)lr[t] * Dh);
    float p1 = 0.f, p2 = 0.f;
#pragma unroll
    for (int k4 = 0; k4 < 16; k4++) {
      float4 e = ep[k4], r = rp[k4];
      const float* u0 = &uv[k4 * 4];        const float* t0 = &tgtE[k4 * 4];
      const float* u1 = &uv[64 + k4 * 4];   const float* t1 = &tgtE[64 + k4 * 4];
      p1 += e.x * u0[0] + e.y * u0[1] + e.z * u0[2] + e.w * u0[3]
          + r.x * u1[0] + r.y * u1[1] + r.z * u1[2] + r.w * u1[3];
      p2 += e.x * t0[0] + e.y * t0[1] + e.z * t0[2] + e.w * t0[3]
          + r.x * t1[0] + r.y * t1[1] + r.z * t1[2] + r.w * t1[3];
    }
    sc1 = p1; sc2 = p2;
    ea = (li[tid] != tgt_i) ? __expf(acc) : 0.f;  // masked exp(score)
  }

  float wsum = ea;
  for (int off = 32; off > 0; off >>= 1) wsum += __shfl_down(wsum, off, 64);
  if (lane == 0) red[wave] = wsum;
  __syncthreads();
  float esum = red[0] + red[1] + red[2] + red[3];
  float inv = esum > 0.f ? 1.f / sqrtf(esum) : 0.f;  // exp_sum ** 0.5 (BETA)

  float part = 0.f;
  if (tid < Hn) {
    float attn = ea * inv;
    float gc = g[tid]; gc = gc > 0.f ? gc : 0.f;  // relu
    float dm = dist_mat[(size_t)i * Hn + tid];
    float geo = __expf(-dm / (gc + 1.f));
    part = (attn + geo) * sc1 + hv[tid] * sc2;
  }
  __syncthreads();  // protect red[] reuse
  for (int off = 32; off > 0; off >>= 1) part += __shfl_down(part, off, 64);
  if (lane == 0) red[wave] = part;
  __syncthreads();
  if (tid == 0) {
    float pred = red[0] + red[1] + red[2] + red[3];
    out[i] = 1.f / (1.f + __expf(-pred));
  }
}

extern "C" void kernel_launch(void* const* d_in, const int* in_sizes, int n_in,
                              void* d_out, int out_size, void* d_ws, size_t ws_size,
                              hipStream_t stream) {
  const int*   history = (const int*)d_in[0];
  const int*   target  = (const int*)d_in[1];
  const int*   hregion = (const int*)d_in[2];
  const int*   tregion = (const int*)d_in[3];
  const float* hv      = (const float*)d_in[4];
  const float* dist    = (const float*)d_in[5];
  const int*   uid     = (const int*)d_in[6];
  const float* Et      = (const float*)d_in[7];
  const float* Er      = (const float*)d_in[8];
  const float* Edist   = (const float*)d_in[9];
  const float* Wq      = (const float*)d_in[10];
  const float* Wk      = (const float*)d_in[11];
  const float* Wv      = (const float*)d_in[12];

  float* g = (float*)d_ws;                          // 200 f32 (1KB slot)
  USH* A   = (USH*)((char*)d_ws + 1024);            // 50000*128 bf16 = 12.8MB
  USH* Bt  = A + (size_t)NITEM * Dn;                // 1000*128 bf16 = 256KB
  float* out = (float*)d_out;

  hipMemsetAsync(g, 0, Hn * sizeof(float), stream);
  g_kernel<<<Bn / 16, 256, 0, stream>>>(hregion, tregion, Edist, uid, g);
  ab_kernel<<<AB_A_BLOCKS + AB_B_BLOCKS, 256, 0, stream>>>(Et, Er, Wk, A, Bt);
  main_kernel<<<Bn, 256, 0, stream>>>(history, target, hregion, tregion, hv, dist,
                                      Et, Er, Wq, Wv, g, A, Bt, out);
}

// Round 7
// 176.066 us; speedup vs baseline: 1.3548x; 1.0225x over previous
//
#include <hip/hip_runtime.h>

typedef unsigned short USH;
typedef unsigned int   UIN;

static constexpr int Bn = 1024;    // batch
static constexpr int Hn = 200;     // history length
static constexpr int Dn = 128;     // embed/hidden
static constexpr int Dh = 64;      // half embed
static constexpr int NITEM = 50000;
static constexpr int NREG  = 1000;
static constexpr int MT = 64;      // items per ab block
static constexpr int AB_A_BLOCKS = (NITEM + MT - 1) / MT;  // 782
static constexpr int AB_B_BLOCKS = (NREG  + MT - 1) / MT;  // 16
static constexpr int WTS = 132;    // wt stride (floats)
static constexpr int ETS = 69;     // et stride (floats)

__device__ __forceinline__ float bf2f(USH u) {
  return __uint_as_float(((UIN)u) << 16);
}
__device__ __forceinline__ float2 pb2f2(UIN p) {  // packed bf16 pair -> 2 floats
  float2 r;
  r.x = __uint_as_float(p << 16);
  r.y = __uint_as_float(p & 0xffff0000u);
  return r;
}
__device__ __forceinline__ USH f2b(float f) {  // fp32 -> bf16 rne
  UIN x = __float_as_uint(f);
  return (USH)((x + 0x7fffu + ((x >> 16) & 1u)) >> 16);
}
__device__ __forceinline__ UIN addpk(UIN u, UIN v) {  // bf16x2 + bf16x2
  float2 a = pb2f2(u), b = pb2f2(v);
  return (UIN)f2b(a.x + b.x) | ((UIN)f2b(a.y + b.y) << 16);
}

// ---------------------------------------------------------------------------
// g[c] = sum_i row[tr[i]] * row[hr[i,c]],  row = embed_dist[uid]  (fp32)
// ---------------------------------------------------------------------------
__global__ __launch_bounds__(256) void g_kernel(
    const int* __restrict__ hregion, const int* __restrict__ tregion,
    const float* __restrict__ embed_dist, const int* __restrict__ uid,
    float* __restrict__ g) {
  int c = threadIdx.x;
  const float* row = embed_dist + (size_t)uid[0] * NREG;  // 4KB, L1-resident
  float acc = 0.f;
  int ibase = blockIdx.x * 16;
  for (int ii = 0; ii < 16; ii++) {
    int i = ibase + ii;
    float td = row[tregion[i]];               // wave-uniform broadcast
    if (c < Hn) acc += td * row[hregion[(size_t)i * Hn + c]];
  }
  if (c < Hn) atomicAdd(&g[c], acc);
}

// ---------------------------------------------------------------------------
// A[item][j] = dot(Et[item][0:64], Wk[j][0:64])   -> bf16 table
// B[reg][j]  = dot(Er[reg][0:64],  Wk[j][64:128]) -> bf16 table
// Register-tiled GEMM (accumulator tile 4x8 cannot be rematerialized).
// v7: also emits bf16 copies of the raw E rows (Eb) from the already-staged
// et[] LDS, so main's s1/s2 gathers read 128B rows instead of 256B fp32.
// ---------------------------------------------------------------------------
__global__ __launch_bounds__(256, 2) void ab_kernel(
    const float* __restrict__ Et, const float* __restrict__ Er,
    const float* __restrict__ Wk, USH* __restrict__ A, USH* __restrict__ Bt,
    USH* __restrict__ Ebr, USH* __restrict__ Err, int emit_raw) {
  __shared__ float wt[64 * WTS];  // 33.8KB: wt[k*WTS + j] = Wk[j][koff+k]
  __shared__ float et[MT * ETS];  // 17.7KB: et[m*ETS + k] = E[base+m][k]
  int blk = blockIdx.x, tid = threadIdx.x;
  const float* E; USH* Out; USH* OutR; int nmax, base, koff;
  if (blk < AB_A_BLOCKS) { E = Et; Out = A;  OutR = Ebr; nmax = NITEM; base = blk * MT; koff = 0; }
  else { E = Er; Out = Bt; OutR = Err; nmax = NREG; base = (blk - AB_A_BLOCKS) * MT; koff = 64; }

  // stage Wk transposed
#pragma unroll
  for (int p = 0; p < 8; p++) {
    int idx = p * 256 + tid;
    int row = idx >> 4, c4 = idx & 15;
    float4 w = *reinterpret_cast<const float4*>(Wk + (size_t)row * Dn + koff + c4 * 4);
    wt[(c4 * 4 + 0) * WTS + row] = w.x;
    wt[(c4 * 4 + 1) * WTS + row] = w.y;
    wt[(c4 * 4 + 2) * WTS + row] = w.z;
    wt[(c4 * 4 + 3) * WTS + row] = w.w;
  }
  // stage E rows row-major
#pragma unroll
  for (int p = 0; p < 4; p++) {
    int idx = p * 256 + tid;
    int m = idx >> 4, c4 = idx & 15;
    int gi = base + m;
    float4 e = make_float4(0.f, 0.f, 0.f, 0.f);
    if (gi < nmax) e = *reinterpret_cast<const float4*>(E + (size_t)gi * Dh + c4 * 4);
    et[m * ETS + c4 * 4 + 0] = e.x;
    et[m * ETS + c4 * 4 + 1] = e.y;
    et[m * ETS + c4 * 4 + 2] = e.z;
    et[m * ETS + c4 * 4 + 3] = e.w;
  }
  __syncthreads();

  // bf16 copy of raw E rows (for main's s1/s2): 64 items x 32 packed uints
  if (emit_raw) {
#pragma unroll
    for (int q = 0; q < 8; q++) {
      int idx = q * 256 + tid;       // 0..2047
      int m = idx >> 5, kp = idx & 31;
      int gi = base + m;
      if (gi < nmax) {
        UIN pk = (UIN)f2b(et[m * ETS + 2 * kp]) | ((UIN)f2b(et[m * ETS + 2 * kp + 1]) << 16);
        *reinterpret_cast<UIN*>(OutR + (size_t)gi * Dh + 2 * kp) = pk;
      }
    }
  }

  int jt = tid & 15, it = tid >> 4;     // 8 j's, 4 items per thread
  const float* wb = wt + jt * 8;
  const float* eb = et + (it * 4) * ETS;
  float c[4][8];
#pragma unroll
  for (int ii = 0; ii < 4; ii++)
#pragma unroll
    for (int jj = 0; jj < 8; jj++) c[ii][jj] = 0.f;

#pragma unroll 2
  for (int k = 0; k < 64; k++) {
    float4 w0 = *reinterpret_cast<const float4*>(wb + (size_t)k * WTS);
    float4 w1 = *reinterpret_cast<const float4*>(wb + (size_t)k * WTS + 4);
    float e0 = eb[k], e1 = eb[ETS + k], e2 = eb[2 * ETS + k], e3 = eb[3 * ETS + k];
    c[0][0] += e0 * w0.x; c[0][1] += e0 * w0.y; c[0][2] += e0 * w0.z; c[0][3] += e0 * w0.w;
    c[0][4] += e0 * w1.x; c[0][5] += e0 * w1.y; c[0][6] += e0 * w1.z; c[0][7] += e0 * w1.w;
    c[1][0] += e1 * w0.x; c[1][1] += e1 * w0.y; c[1][2] += e1 * w0.z; c[1][3] += e1 * w0.w;
    c[1][4] += e1 * w1.x; c[1][5] += e1 * w1.y; c[1][6] += e1 * w1.z; c[1][7] += e1 * w1.w;
    c[2][0] += e2 * w0.x; c[2][1] += e2 * w0.y; c[2][2] += e2 * w0.z; c[2][3] += e2 * w0.w;
    c[2][4] += e2 * w1.x; c[2][5] += e2 * w1.y; c[2][6] += e2 * w1.z; c[2][7] += e2 * w1.w;
    c[3][0] += e3 * w0.x; c[3][1] += e3 * w0.y; c[3][2] += e3 * w0.z; c[3][3] += e3 * w0.w;
    c[3][4] += e3 * w1.x; c[3][5] += e3 * w1.y; c[3][6] += e3 * w1.z; c[3][7] += e3 * w1.w;
  }

#pragma unroll
  for (int ii = 0; ii < 4; ii++) {
    int item = base + it * 4 + ii;
    if (item < nmax) {
      uint4 pk;
      pk.x = (UIN)f2b(c[ii][0]) | ((UIN)f2b(c[ii][1]) << 16);
      pk.y = (UIN)f2b(c[ii][2]) | ((UIN)f2b(c[ii][3]) << 16);
      pk.z = (UIN)f2b(c[ii][4]) | ((UIN)f2b(c[ii][5]) << 16);
      pk.w = (UIN)f2b(c[ii][6]) | ((UIN)f2b(c[ii][7]) << 16);
      *reinterpret_cast<uint4*>(Out + (size_t)item * Dn + jt * 8) = pk;
    }
  }
}

// ---------------------------------------------------------------------------
// One block per batch row i. v7: LDS diet (52.8KB -> 3 blocks/CU), uint4
// staging (16 lanes/row, 13 unrolled passes, ~26 loads in flight), s1/s2
// from bf16 raw tables when available.
// ---------------------------------------------------------------------------
__global__ __launch_bounds__(256, 3) void main_kernel(
    const int* __restrict__ history, const int* __restrict__ target,
    const int* __restrict__ hregion, const int* __restrict__ tregion,
    const float* __restrict__ hv, const float* __restrict__ dist_mat,
    const float* __restrict__ Et, const float* __restrict__ Er,
    const float* __restrict__ Wq, const float* __restrict__ Wv,
    const float* __restrict__ g, const USH* __restrict__ A,
    const USH* __restrict__ Bt, const USH* __restrict__ Ebr,
    const USH* __restrict__ Err, int use_raw, float* __restrict__ out) {
  __shared__ USH kvs[Hn * Dn];      // 51200B: kv[t][j] bf16
  __shared__ float tgtE[128], qv[128], uv[128];
  __shared__ float red[8];          // total 52832B -> 3 blocks/CU
  int i = blockIdx.x, tid = threadIdx.x, lane = tid & 63, wave = tid >> 6;
  int tgt_i = target[i], tr_i = tregion[i];
  const int* hrow = history + (size_t)i * Hn;
  const int* rrow = hregion + (size_t)i * Hn;

  if (tid < 64)       tgtE[tid] = Et[(size_t)tgt_i * Dh + tid];
  else if (tid < 128) tgtE[tid] = Er[(size_t)tr_i * Dh + (tid - 64)];

  // ---- stage kv[t][j] = A[li[t]][j] + B[lr[t]][j] (bf16), 16B/lane ----
  {
    int rlane = tid & 15, rgrp = tid >> 4;   // 16 rows per pass
#pragma unroll
    for (int p = 0; p < 13; p++) {
      int t = p * 16 + rgrp;
      if (t < Hn) {
        int ia = hrow[t], ib = rrow[t];      // L1-hot after first pass
        uint4 av = *reinterpret_cast<const uint4*>(A  + (size_t)ia * Dn + rlane * 8);
        uint4 bv = *reinterpret_cast<const uint4*>(Bt + (size_t)ib * Dn + rlane * 8);
        uint4 pk;
        pk.x = addpk(av.x, bv.x); pk.y = addpk(av.y, bv.y);
        pk.z = addpk(av.z, bv.z); pk.w = addpk(av.w, bv.w);
        *reinterpret_cast<uint4*>(&kvs[t * Dn + rlane * 8]) = pk;
      }
    }
  }
  __syncthreads();  // tgtE ready (kvs not yet needed below until next sync)

  // ---- qv (waves 0-1) / uv (waves 2-3) ----
  if (tid < 128) {
    int j = tid; float acc = 0.f;
    const float4* wp = reinterpret_cast<const float4*>(Wq + (size_t)j * Dn);
#pragma unroll
    for (int q4 = 0; q4 < 32; q4++) {
      float4 w = wp[q4];
      const float* tv = &tgtE[q4 * 4];
      acc += w.x * tv[0] + w.y * tv[1] + w.z * tv[2] + w.w * tv[3];
    }
    qv[j] = acc * 0.088388347648318447f;  // 1/sqrt(128) folded into q
  } else {
    int d = tid - 128;
    float a0 = 0.f, a1 = 0.f, a2 = 0.f, a3 = 0.f;
#pragma unroll 8
    for (int j = 0; j < 128; j += 4) {
      a0 += Wv[(size_t)(j + 0) * Dn + d] * tgtE[j + 0];
      a1 += Wv[(size_t)(j + 1) * Dn + d] * tgtE[j + 1];
      a2 += Wv[(size_t)(j + 2) * Dn + d] * tgtE[j + 2];
      a3 += Wv[(size_t)(j + 3) * Dn + d] * tgtE[j + 3];
    }
    uv[d] = (a0 + a1) + (a2 + a3);
  }
  __syncthreads();

  float ea = 0.f, sc1 = 0.f, sc2 = 0.f;
  if (tid < Hn) {
    // scores[c]: kvs halfword index == m == a*200+c (zero address math)
    int c = tid;
    float acc = 0.f;
    const USH* kp = &kvs[c];
#pragma unroll 16
    for (int a = 0; a < 128; a++) acc += qv[a] * bf2f(kp[a * 200]);
    // s1/s2: per-thread dot over own history row
    int ia2 = hrow[tid], ib2 = rrow[tid];
    float p1 = 0.f, p2 = 0.f;
    if (use_raw) {
      const uint4* epu = reinterpret_cast<const uint4*>(Ebr + (size_t)ia2 * Dh);
      const uint4* rpu = reinterpret_cast<const uint4*>(Err + (size_t)ib2 * Dh);
#pragma unroll
      for (int k8 = 0; k8 < 8; k8++) {
        uint4 e = epu[k8], r = rpu[k8];
        float2 e0 = pb2f2(e.x), e1 = pb2f2(e.y), e2 = pb2f2(e.z), e3 = pb2f2(e.w);
        float2 r0 = pb2f2(r.x), r1 = pb2f2(r.y), r2 = pb2f2(r.z), r3 = pb2f2(r.w);
        const float* u0 = &uv[k8 * 8];       const float* t0 = &tgtE[k8 * 8];
        const float* u1 = &uv[64 + k8 * 8];  const float* t1 = &tgtE[64 + k8 * 8];
        p1 += e0.x * u0[0] + e0.y * u0[1] + e1.x * u0[2] + e1.y * u0[3]
            + e2.x * u0[4] + e2.y * u0[5] + e3.x * u0[6] + e3.y * u0[7]
            + r0.x * u1[0] + r0.y * u1[1] + r1.x * u1[2] + r1.y * u1[3]
            + r2.x * u1[4] + r2.y * u1[5] + r3.x * u1[6] + r3.y * u1[7];
        p2 += e0.x * t0[0] + e0.y * t0[1] + e1.x * t0[2] + e1.y * t0[3]
            + e2.x * t0[4] + e2.y * t0[5] + e3.x * t0[6] + e3.y * t0[7]
            + r0.x * t1[0] + r0.y * t1[1] + r1.x * t1[2] + r1.y * t1[3]
            + r2.x * t1[4] + r2.y * t1[5] + r3.x * t1[6] + r3.y * t1[7];
      }
    } else {
      const float4* ep = reinterpret_cast<const float4*>(Et + (size_t)ia2 * Dh);
      const float4* rp = reinterpret_cast<const float4*>(Er + (size_t)ib2 * Dh);
#pragma unroll
      for (int k4 = 0; k4 < 16; k4++) {
        float4 e = ep[k4], r = rp[k4];
        const float* u0 = &uv[k4 * 4];        const float* t0 = &tgtE[k4 * 4];
        const float* u1 = &uv[64 + k4 * 4];   const float* t1 = &tgtE[64 + k4 * 4];
        p1 += e.x * u0[0] + e.y * u0[1] + e.z * u0[2] + e.w * u0[3]
            + r.x * u1[0] + r.y * u1[1] + r.z * u1[2] + r.w * u1[3];
        p2 += e.x * t0[0] + e.y * t0[1] + e.z * t0[2] + e.w * t0[3]
            + r.x * t1[0] + r.y * t1[1] + r.z * t1[2] + r.w * t1[3];
      }
    }
    sc1 = p1; sc2 = p2;
    ea = (ia2 != tgt_i) ? __expf(acc) : 0.f;  // masked exp(score)
  }

  float wsum = ea;
  for (int off = 32; off > 0; off >>= 1) wsum += __shfl_down(wsum, off, 64);
  if (lane == 0) red[wave] = wsum;
  __syncthreads();
  float esum = red[0] + red[1] + red[2] + red[3];
  float inv = esum > 0.f ? 1.f / sqrtf(esum) : 0.f;  // exp_sum ** 0.5 (BETA)

  float part = 0.f;
  if (tid < Hn) {
    float attn = ea * inv;
    float gc = g[tid]; gc = gc > 0.f ? gc : 0.f;  // relu
    float dm = dist_mat[(size_t)i * Hn + tid];
    float geo = __expf(-dm / (gc + 1.f));
    part = (attn + geo) * sc1 + hv[tid] * sc2;
  }
  __syncthreads();  // protect red[] reuse
  for (int off = 32; off > 0; off >>= 1) part += __shfl_down(part, off, 64);
  if (lane == 0) red[wave] = part;
  __syncthreads();
  if (tid == 0) {
    float pred = red[0] + red[1] + red[2] + red[3];
    out[i] = 1.f / (1.f + __expf(-pred));
  }
}

extern "C" void kernel_launch(void* const* d_in, const int* in_sizes, int n_in,
                              void* d_out, int out_size, void* d_ws, size_t ws_size,
                              hipStream_t stream) {
  const int*   history = (const int*)d_in[0];
  const int*   target  = (const int*)d_in[1];
  const int*   hregion = (const int*)d_in[2];
  const int*   tregion = (const int*)d_in[3];
  const float* hv      = (const float*)d_in[4];
  const float* dist    = (const float*)d_in[5];
  const int*   uid     = (const int*)d_in[6];
  const float* Et      = (const float*)d_in[7];
  const float* Er      = (const float*)d_in[8];
  const float* Edist   = (const float*)d_in[9];
  const float* Wq      = (const float*)d_in[10];
  const float* Wk      = (const float*)d_in[11];
  const float* Wv      = (const float*)d_in[12];

  float* g = (float*)d_ws;                          // 200 f32 (1KB slot)
  USH* A   = (USH*)((char*)d_ws + 1024);            // 50000*128 bf16 = 12.8MB
  USH* Bt  = A + (size_t)NITEM * Dn;                // 1000*128 bf16
  USH* Ebr = Bt + (size_t)NREG * Dn;                // 50000*64 bf16 = 6.4MB
  USH* Err = Ebr + (size_t)NITEM * Dh;              // 1000*64 bf16
  size_t need_raw = 1024 + 2 * ((size_t)NITEM * Dn + (size_t)NREG * Dn +
                                (size_t)NITEM * Dh + (size_t)NREG * Dh);
  int use_raw = (ws_size >= need_raw) ? 1 : 0;
  float* out = (float*)d_out;

  hipMemsetAsync(g, 0, Hn * sizeof(float), stream);
  g_kernel<<<Bn / 16, 256, 0, stream>>>(hregion, tregion, Edist, uid, g);
  ab_kernel<<<AB_A_BLOCKS + AB_B_BLOCKS, 256, 0, stream>>>(Et, Er, Wk, A, Bt,
                                                           Ebr, Err, use_raw);
  main_kernel<<<Bn, 256, 0, stream>>>(history, target, hregion, tregion, hv, dist,
                                      Et, Er, Wq, Wv, g, A, Bt, Ebr, Err, use_raw,
                                      out);
}